// Round 1
// baseline (1304.308 us; speedup 1.0000x reference)
//
#include <hip/hip_runtime.h>
#include <cstdint>
#include <cstddef>

// DeltaMPredictor: proj(2048->512) + per-cam LN + per-cam SwiGLU + proj->36
// + skew/clip/expm(6x6). bf16 MFMA for all GEMMs (threshold 1.99e-2 absolute),
// fp32 for LN stats and expm.
//
// B=16384, C=4, D_BB=2048, D=512. Output [C,B,6,6] fp32.
// ws usage: ~140.7 MB (regb/hb share 64MiB @0; xnb/Abuf share @64MiB; weights @128MiB)

#define B_SZ   16384
#define C_CAM  4
#define DBB    2048
#define D_H    512

typedef __attribute__((ext_vector_type(8))) short  bf16x8;
typedef __attribute__((ext_vector_type(4))) float  f32x4;

__device__ __forceinline__ unsigned short f2b(float f) {
    union { float f; unsigned u; } v; v.f = f;
    unsigned r = (v.u + 0x7FFFu + ((v.u >> 16) & 1u)) >> 16;   // RNE
    return (unsigned short)r;
}
__device__ __forceinline__ float b2f(unsigned short u) {
    union { unsigned u; float f; } v; v.u = ((unsigned)u) << 16;
    return v.f;
}

// ---------------- weight conversion ----------------
__global__ void k_cvt(const float* __restrict__ src, unsigned short* __restrict__ dst, int n) {
    int i = blockIdx.x * blockDim.x + threadIdx.x;
    int stride = gridDim.x * blockDim.x;
    for (; i < n; i += stride) dst[i] = f2b(src[i]);
}

// w_out [C,36,512] -> bf16 padded to [C,48,512], rows 36..47 zero
__global__ void k_cvt_wout(const float* __restrict__ src, unsigned short* __restrict__ dst) {
    int i = blockIdx.x * blockDim.x + threadIdx.x;
    if (i >= C_CAM * 48 * D_H) return;
    int col = i & (D_H - 1);
    int row = (i >> 9) % 48;
    int c   = i / (48 * D_H);
    dst[i] = (row < 36) ? f2b(src[((size_t)c * 36 + row) * D_H + col]) : (unsigned short)0;
}

// ---------------- K1: projection GEMM (fp32 A converted in staging) ----------------
// C[M=65536, N=512] = A[M,2048] * W[512,2048]^T + bias ; output bf16
// grid (4 n-strips fastest for L3 reuse of A, 512 m-strips), 256 thr = 4 waves,
// tile 128x128x64, each wave 64x64 (4x4 mfma frags)
__global__ __launch_bounds__(256)
void k_proj(const float* __restrict__ A, const unsigned short* __restrict__ Bw,
            const float* __restrict__ bias, unsigned short* __restrict__ regb) {
    __shared__ unsigned short lsA[128 * 72];   // +8 pad: 2-way-max bank aliasing
    __shared__ unsigned short lsB[128 * 72];
    const int t = threadIdx.x;
    const int tile_n = blockIdx.x * 128;
    const int tile_m = blockIdx.y * 128;
    const int w = t >> 6, l = t & 63, lr = l & 15, quad = l >> 4;
    const int wm = (w >> 1) * 64, wn = (w & 1) * 64;

    f32x4 acc[4][4];
#pragma unroll
    for (int i = 0; i < 4; i++)
#pragma unroll
        for (int j = 0; j < 4; j++) acc[i][j] = (f32x4){0.f, 0.f, 0.f, 0.f};

    const int ar = t >> 4, ac = (t & 15) * 4;   // A: 16 thr/row, 4 floats each
    const int br = t >> 3, bc = (t & 7) * 8;    // B: 8 thr/row, 8 bf16 each

    for (int kt = 0; kt < DBB / 64; ++kt) {
        __syncthreads();
#pragma unroll
        for (int p = 0; p < 8; p++) {
            const int row = p * 16 + ar;
            const float4 v = *(const float4*)(A + (size_t)(tile_m + row) * DBB + kt * 64 + ac);
            unsigned p0 = (unsigned)f2b(v.x) | ((unsigned)f2b(v.y) << 16);
            unsigned p1 = (unsigned)f2b(v.z) | ((unsigned)f2b(v.w) << 16);
            *(uint2*)(&lsA[row * 72 + ac]) = make_uint2(p0, p1);
        }
#pragma unroll
        for (int p = 0; p < 4; p++) {
            const int row = p * 32 + br;
            *(uint4*)(&lsB[row * 72 + bc]) =
                *(const uint4*)(Bw + (size_t)(tile_n + row) * DBB + kt * 64 + bc);
        }
        __syncthreads();
#pragma unroll
        for (int kk = 0; kk < 2; ++kk) {
            bf16x8 af[4], bfr[4];
#pragma unroll
            for (int i = 0; i < 4; i++)
                af[i] = *(const bf16x8*)(&lsA[(wm + i * 16 + lr) * 72 + kk * 32 + quad * 8]);
#pragma unroll
            for (int j = 0; j < 4; j++)
                bfr[j] = *(const bf16x8*)(&lsB[(wn + j * 16 + lr) * 72 + kk * 32 + quad * 8]);
#pragma unroll
            for (int i = 0; i < 4; i++)
#pragma unroll
                for (int j = 0; j < 4; j++)
                    acc[i][j] = __builtin_amdgcn_mfma_f32_16x16x32_bf16(af[i], bfr[j], acc[i][j], 0, 0, 0);
        }
    }
    // epilogue: + bias, -> bf16. D layout: row = quad*4+r, col = lane&15
#pragma unroll
    for (int j = 0; j < 4; j++) {
        const int col = tile_n + wn + j * 16 + lr;
        const float bv = bias[col];
#pragma unroll
        for (int i = 0; i < 4; i++)
#pragma unroll
            for (int r = 0; r < 4; r++) {
                const int row = tile_m + wm + i * 16 + quad * 4 + r;
                regb[(size_t)row * D_H + col] = f2b(acc[i][j][r] + bv);
            }
    }
}

// ---------------- K2: LayerNorm (one wave per row) ----------------
// reads reg bf16 [B*C, 512] (row r: b=r>>2, c=r&3), writes xn bf16 camera-major [C,B,512]
__global__ __launch_bounds__(256)
void k_ln(const unsigned short* __restrict__ regb, const float* __restrict__ gamma,
          const float* __restrict__ beta, unsigned short* __restrict__ xnb) {
    const int t = threadIdx.x;
    const int wave = t >> 6, l = t & 63;
    const int r = blockIdx.x * 4 + wave;
    const int c = r & 3, b = r >> 2;

    const uint4 pk = *(const uint4*)(regb + (size_t)r * D_H + l * 8);
    const unsigned short* ps = (const unsigned short*)&pk;
    float x[8];
#pragma unroll
    for (int j = 0; j < 8; j++) x[j] = b2f(ps[j]);

    float s = 0.f, ss = 0.f;
#pragma unroll
    for (int j = 0; j < 8; j++) { s += x[j]; ss += x[j] * x[j]; }
#pragma unroll
    for (int off = 32; off > 0; off >>= 1) {
        s  += __shfl_xor(s, off);
        ss += __shfl_xor(ss, off);
    }
    const float mu  = s * (1.0f / 512.0f);
    const float var = ss * (1.0f / 512.0f) - mu * mu;
    const float rs  = rsqrtf(var + 1e-5f);

    unsigned short o[8];
#pragma unroll
    for (int j = 0; j < 8; j++) {
        const int d = l * 8 + j;
        o[j] = f2b((x[j] - mu) * rs * gamma[c * D_H + d] + beta[c * D_H + d]);
    }
    *(uint4*)(xnb + ((size_t)c * B_SZ + b) * D_H + l * 8) = *(const uint4*)o;
}

// ---------------- K3: per-camera fused gate/val GEMM + SiLU ----------------
// per cam: gate/val[16384,512] = xn[16384,512] * W[512,512]^T ; h = silu(g)*v -> bf16
__global__ __launch_bounds__(256)
void k_swiglu(const unsigned short* __restrict__ xnb, const unsigned short* __restrict__ wg,
              const unsigned short* __restrict__ wv, unsigned short* __restrict__ hb) {
    __shared__ unsigned short lsA[128 * 72];
    __shared__ unsigned short lsG[128 * 72];
    __shared__ unsigned short lsV[128 * 72];
    const int t = threadIdx.x;
    const int tile_n = blockIdx.x * 128;
    const int tile_m = blockIdx.y * 128;
    const int cam = blockIdx.z;
    const unsigned short* Ac = xnb + (size_t)cam * B_SZ * D_H;
    const unsigned short* Gc = wg + (size_t)cam * D_H * D_H;
    const unsigned short* Vc = wv + (size_t)cam * D_H * D_H;
    const int w = t >> 6, l = t & 63, lr = l & 15, quad = l >> 4;
    const int wm = (w >> 1) * 64, wn = (w & 1) * 64;

    f32x4 ag[4][4], av[4][4];
#pragma unroll
    for (int i = 0; i < 4; i++)
#pragma unroll
        for (int j = 0; j < 4; j++) { ag[i][j] = (f32x4){0.f,0.f,0.f,0.f}; av[i][j] = (f32x4){0.f,0.f,0.f,0.f}; }

    const int br = t >> 3, bc = (t & 7) * 8;

    for (int kt = 0; kt < D_H / 64; ++kt) {
        __syncthreads();
#pragma unroll
        for (int p = 0; p < 4; p++) {
            const int row = p * 32 + br;
            *(uint4*)(&lsA[row * 72 + bc]) =
                *(const uint4*)(Ac + (size_t)(tile_m + row) * D_H + kt * 64 + bc);
            *(uint4*)(&lsG[row * 72 + bc]) =
                *(const uint4*)(Gc + (size_t)(tile_n + row) * D_H + kt * 64 + bc);
            *(uint4*)(&lsV[row * 72 + bc]) =
                *(const uint4*)(Vc + (size_t)(tile_n + row) * D_H + kt * 64 + bc);
        }
        __syncthreads();
#pragma unroll
        for (int kk = 0; kk < 2; ++kk) {
            bf16x8 af[4];
#pragma unroll
            for (int i = 0; i < 4; i++)
                af[i] = *(const bf16x8*)(&lsA[(wm + i * 16 + lr) * 72 + kk * 32 + quad * 8]);
#pragma unroll
            for (int j = 0; j < 4; j++) {
                bf16x8 gf = *(const bf16x8*)(&lsG[(wn + j * 16 + lr) * 72 + kk * 32 + quad * 8]);
                bf16x8 vf = *(const bf16x8*)(&lsV[(wn + j * 16 + lr) * 72 + kk * 32 + quad * 8]);
#pragma unroll
                for (int i = 0; i < 4; i++) {
                    ag[i][j] = __builtin_amdgcn_mfma_f32_16x16x32_bf16(af[i], gf, ag[i][j], 0, 0, 0);
                    av[i][j] = __builtin_amdgcn_mfma_f32_16x16x32_bf16(af[i], vf, av[i][j], 0, 0, 0);
                }
            }
        }
    }
#pragma unroll
    for (int i = 0; i < 4; i++)
#pragma unroll
        for (int j = 0; j < 4; j++)
#pragma unroll
            for (int r = 0; r < 4; r++) {
                const int row = tile_m + wm + i * 16 + quad * 4 + r;
                const int col = tile_n + wn + j * 16 + lr;
                const float g = ag[i][j][r], v = av[i][j][r];
                const float h = g * v / (1.0f + __expf(-g));   // silu(g)*v
                hb[((size_t)cam * B_SZ + row) * D_H + col] = f2b(h);
            }
}

// ---------------- K4: per-camera out-proj (N padded 36->48) ----------------
__global__ __launch_bounds__(256)
void k_outproj(const unsigned short* __restrict__ hb, const unsigned short* __restrict__ wo,
               float* __restrict__ Abuf) {
    __shared__ unsigned short lsA[128 * 72];
    __shared__ unsigned short lsB[48 * 72];
    const int t = threadIdx.x;
    const int tile_m = blockIdx.y * 128;
    const int cam = blockIdx.z;
    const unsigned short* Ac = hb + (size_t)cam * B_SZ * D_H;
    const unsigned short* Bc = wo + (size_t)cam * 48 * D_H;
    const int w = t >> 6, l = t & 63, lr = l & 15, quad = l >> 4;

    f32x4 acc[2][3];
#pragma unroll
    for (int i = 0; i < 2; i++)
#pragma unroll
        for (int j = 0; j < 3; j++) acc[i][j] = (f32x4){0.f,0.f,0.f,0.f};

    const int br = t >> 3, bc = (t & 7) * 8;

    for (int kt = 0; kt < D_H / 64; ++kt) {
        __syncthreads();
#pragma unroll
        for (int p = 0; p < 4; p++) {
            const int row = p * 32 + br;
            *(uint4*)(&lsA[row * 72 + bc]) =
                *(const uint4*)(Ac + (size_t)(tile_m + row) * D_H + kt * 64 + bc);
        }
#pragma unroll
        for (int p = 0; p < 2; p++) {
            const int flat = (p * 256 + t) * 8;
            if (flat < 48 * 64) {
                const int row = flat >> 6, col = flat & 63;
                *(uint4*)(&lsB[row * 72 + col]) =
                    *(const uint4*)(Bc + (size_t)row * D_H + kt * 64 + col);
            }
        }
        __syncthreads();
#pragma unroll
        for (int kk = 0; kk < 2; ++kk) {
            bf16x8 af[2], bfr[3];
#pragma unroll
            for (int i = 0; i < 2; i++)
                af[i] = *(const bf16x8*)(&lsA[(w * 32 + i * 16 + lr) * 72 + kk * 32 + quad * 8]);
#pragma unroll
            for (int j = 0; j < 3; j++)
                bfr[j] = *(const bf16x8*)(&lsB[(j * 16 + lr) * 72 + kk * 32 + quad * 8]);
#pragma unroll
            for (int i = 0; i < 2; i++)
#pragma unroll
                for (int j = 0; j < 3; j++)
                    acc[i][j] = __builtin_amdgcn_mfma_f32_16x16x32_bf16(af[i], bfr[j], acc[i][j], 0, 0, 0);
        }
    }
#pragma unroll
    for (int i = 0; i < 2; i++)
#pragma unroll
        for (int j = 0; j < 3; j++)
#pragma unroll
            for (int r = 0; r < 4; r++) {
                const int col = j * 16 + lr;
                if (col < 36) {
                    const int row = tile_m + w * 32 + i * 16 + quad * 4 + r;
                    Abuf[((size_t)cam * B_SZ + row) * 36 + col] = acc[i][j][r];
                }
            }
}

// ---------------- K5: skew, clip, expm (one thread per 6x6) ----------------
__global__ __launch_bounds__(128)
void k_expm(const float* __restrict__ Abuf, float* __restrict__ out) {
    const int gid = blockIdx.x * blockDim.x + threadIdx.x;
    if (gid >= B_SZ * C_CAM) return;
    const float* Ap = Abuf + (size_t)gid * 36;

    float a[36];
#pragma unroll
    for (int i = 0; i < 36; i++) a[i] = Ap[i];

    float S[36];
#pragma unroll
    for (int i = 0; i < 6; i++)
#pragma unroll
        for (int j = 0; j < 6; j++) S[i * 6 + j] = a[i * 6 + j] - a[j * 6 + i];

    float fr2 = 0.f;
#pragma unroll
    for (int i = 0; i < 36; i++) fr2 += S[i] * S[i];
    const float fr = sqrtf(fr2);
    const float sc = fminf(fr, 3.0f) / fmaxf(fr, 1e-8f) * 0.0625f;   // clip + 2^-4 scaling

    float As[36];
#pragma unroll
    for (int i = 0; i < 36; i++) As[i] = S[i] * sc;

    float E[36], T[36], tmp[36];
#pragma unroll
    for (int i = 0; i < 36; i++) { E[i] = (i % 7 == 0) ? 1.f : 0.f; T[i] = E[i]; }

#pragma unroll
    for (int k = 1; k <= 12; k++) {
        const float invk = 1.0f / (float)k;
#pragma unroll
        for (int i = 0; i < 6; i++)
#pragma unroll
            for (int j = 0; j < 6; j++) {
                float sum = 0.f;
#pragma unroll
                for (int q = 0; q < 6; q++) sum += T[i * 6 + q] * As[q * 6 + j];
                tmp[i * 6 + j] = sum * invk;
            }
#pragma unroll
        for (int i = 0; i < 36; i++) { T[i] = tmp[i]; E[i] += tmp[i]; }
    }
#pragma unroll
    for (int sq = 0; sq < 4; sq++) {
#pragma unroll
        for (int i = 0; i < 6; i++)
#pragma unroll
            for (int j = 0; j < 6; j++) {
                float sum = 0.f;
#pragma unroll
                for (int q = 0; q < 6; q++) sum += E[i * 6 + q] * E[q * 6 + j];
                tmp[i * 6 + j] = sum;
            }
#pragma unroll
        for (int i = 0; i < 36; i++) E[i] = tmp[i];
    }

    float* op = out + (size_t)gid * 36;
#pragma unroll
    for (int i = 0; i < 36; i++) op[i] = E[i];
}

// ---------------- launcher ----------------
extern "C" void kernel_launch(void* const* d_in, const int* in_sizes, int n_in,
                              void* d_out, int out_size, void* d_ws, size_t ws_size,
                              hipStream_t stream) {
    const float* thumb  = (const float*)d_in[0];
    const float* proj_w = (const float*)d_in[1];
    const float* proj_b = (const float*)d_in[2];
    const float* gamma  = (const float*)d_in[3];
    const float* beta   = (const float*)d_in[4];
    const float* w_gate = (const float*)d_in[5];
    const float* w_val  = (const float*)d_in[6];
    const float* w_out  = (const float*)d_in[7];

    char* ws = (char*)d_ws;
    // 0..64Mi: regb, later reused as hb. 64Mi..128Mi: xnb, later reused as Abuf.
    unsigned short* regb = (unsigned short*)(ws + 0);
    unsigned short* xnb  = (unsigned short*)(ws + 67108864);
    unsigned short* hb   = (unsigned short*)(ws + 0);          // reuse (regb dead after k_ln)
    float*          Abuf = (float*)(ws + 67108864);            // reuse (xnb dead after k_swiglu)
    unsigned short* pwb  = (unsigned short*)(ws + 134217728);  // 2 MiB
    unsigned short* wgb  = (unsigned short*)(ws + 136314880);  // 2 MiB
    unsigned short* wvb  = (unsigned short*)(ws + 138412032);  // 2 MiB
    unsigned short* wob  = (unsigned short*)(ws + 140509184);  // 192 KiB

    hipLaunchKernelGGL(k_cvt, dim3(1024), dim3(256), 0, stream, proj_w, pwb, D_H * DBB);
    hipLaunchKernelGGL(k_cvt, dim3(1024), dim3(256), 0, stream, w_gate, wgb, C_CAM * D_H * D_H);
    hipLaunchKernelGGL(k_cvt, dim3(1024), dim3(256), 0, stream, w_val, wvb, C_CAM * D_H * D_H);
    hipLaunchKernelGGL(k_cvt_wout, dim3((C_CAM * 48 * D_H + 255) / 256), dim3(256), 0, stream, w_out, wob);

    hipLaunchKernelGGL(k_proj, dim3(4, 512), dim3(256), 0, stream, thumb, pwb, proj_b, regb);
    hipLaunchKernelGGL(k_ln, dim3(B_SZ * C_CAM / 4), dim3(256), 0, stream, regb, gamma, beta, xnb);
    hipLaunchKernelGGL(k_swiglu, dim3(4, 128, 4), dim3(256), 0, stream, xnb, wgb, wvb, hb);
    hipLaunchKernelGGL(k_outproj, dim3(1, 128, 4), dim3(256), 0, stream, hb, wob, Abuf);
    hipLaunchKernelGGL(k_expm, dim3(B_SZ * C_CAM / 128), dim3(128), 0, stream, Abuf, (float*)d_out);
}

// Round 2
// 1183.251 us; speedup vs baseline: 1.1023x; 1.1023x over previous
//
#include <hip/hip_runtime.h>
#include <cstdint>
#include <cstddef>

// DeltaMPredictor: proj(2048->512) + per-cam LN + per-cam SwiGLU + proj->36
// + skew/clip/expm(6x6). bf16 MFMA GEMMs in m97 structure (global_load_lds
// width=16, BK=32 unpadded tiles), fp32 LN stats and expm.
//
// Fast path needs ~409 MB ws (bf16 copy of thumbnails); falls back to the
// fused-conversion k_proj if ws_size is smaller.

#define B_SZ   16384
#define C_CAM  4
#define DBB    2048
#define D_H    512

typedef __attribute__((ext_vector_type(8))) short  bf16x8;
typedef __attribute__((ext_vector_type(4))) float  f32x4;

__device__ __forceinline__ unsigned short f2b(float f) {
    union { float f; unsigned u; } v; v.f = f;
    unsigned r = (v.u + 0x7FFFu + ((v.u >> 16) & 1u)) >> 16;   // RNE
    return (unsigned short)r;
}
__device__ __forceinline__ float b2f(unsigned short u) {
    union { unsigned u; float f; } v; v.u = ((unsigned)u) << 16;
    return v.f;
}

// async global->LDS, 16B per lane, dest = wave-uniform base + lane*16
#define GLDS(g, l) __builtin_amdgcn_global_load_lds( \
    (const __attribute__((address_space(1))) unsigned int*)(g), \
    (__attribute__((address_space(3))) unsigned int*)(l), 16, 0, 0)

// ---------------- weight / input conversion ----------------
__global__ void k_cvt(const float* __restrict__ src, unsigned short* __restrict__ dst, int n) {
    int i = blockIdx.x * blockDim.x + threadIdx.x;
    int stride = gridDim.x * blockDim.x;
    for (; i < n; i += stride) dst[i] = f2b(src[i]);
}

// 8 elems/thread vectorized fp32->bf16 (for the 536 MB thumbnail tensor)
__global__ __launch_bounds__(256)
void k_cvt8(const float* __restrict__ src, unsigned short* __restrict__ dst, long n8) {
    long i = (long)blockIdx.x * blockDim.x + threadIdx.x;
    if (i >= n8) return;
    const float4 a = ((const float4*)src)[i * 2];
    const float4 b = ((const float4*)src)[i * 2 + 1];
    unsigned short o[8] = {f2b(a.x), f2b(a.y), f2b(a.z), f2b(a.w),
                           f2b(b.x), f2b(b.y), f2b(b.z), f2b(b.w)};
    ((uint4*)dst)[i] = *(const uint4*)o;
}

// w_out [C,36,512] -> bf16 padded to [C,48,512], rows 36..47 zero
__global__ void k_cvt_wout(const float* __restrict__ src, unsigned short* __restrict__ dst) {
    int i = blockIdx.x * blockDim.x + threadIdx.x;
    if (i >= C_CAM * 48 * D_H) return;
    int col = i & (D_H - 1);
    int row = (i >> 9) % 48;
    int c   = i / (48 * D_H);
    dst[i] = (row < 36) ? f2b(src[((size_t)c * 36 + row) * D_H + col]) : (unsigned short)0;
}

// ---------------- K1 fast: bf16 GEMM, m97 structure ----------------
// C[65536,512] = A[65536,2048] * W[512,2048]^T + bias -> bf16
// 128x128 tile, BK=32, LDS tiles [128][32] unpadded (row = 16 dwords -> banks
// 16*(row&1)+4*quad: all 32 banks covered, balanced). 2 GLDS/tile/thread.
__global__ __launch_bounds__(256)
void k_projb(const unsigned short* __restrict__ A, const unsigned short* __restrict__ Bw,
             const float* __restrict__ bias, unsigned short* __restrict__ regb) {
    __shared__ unsigned short lsA[128 * 32];
    __shared__ unsigned short lsB[128 * 32];
    const int t = threadIdx.x;
    const int tile_n = blockIdx.x * 128;
    const int tile_m = blockIdx.y * 128;
    const int w = t >> 6, l = t & 63, lr = l & 15, quad = l >> 4;
    const int wm = (w >> 1) * 64, wn = (w & 1) * 64;

    f32x4 acc[4][4];
#pragma unroll
    for (int i = 0; i < 4; i++)
#pragma unroll
        for (int j = 0; j < 4; j++) acc[i][j] = (f32x4){0.f, 0.f, 0.f, 0.f};

    // staging: instr p of wave w covers rows (w*2+p)*16; lane l -> row +l>>2, 16B chunk l&3
    const int srow = l >> 2, scol = (l & 3) * 8;
    const unsigned short* baseA = A  + (size_t)(tile_m + w * 32 + srow) * DBB + scol;
    const unsigned short* baseB = Bw + (size_t)(tile_n + w * 32 + srow) * DBB + scol;
    unsigned short* ldsAw = &lsA[w * 32 * 32];
    unsigned short* ldsBw = &lsB[w * 32 * 32];

    for (int kt = 0; kt < DBB / 32; ++kt) {
        __syncthreads();
        GLDS(baseA + kt * 32,            ldsAw);
        GLDS(baseA + kt * 32 + 16 * DBB, ldsAw + 16 * 32);
        GLDS(baseB + kt * 32,            ldsBw);
        GLDS(baseB + kt * 32 + 16 * DBB, ldsBw + 16 * 32);
        __syncthreads();
        bf16x8 af[4], bfr[4];
#pragma unroll
        for (int i = 0; i < 4; i++)
            af[i] = *(const bf16x8*)(&lsA[(wm + i * 16 + lr) * 32 + quad * 8]);
#pragma unroll
        for (int j = 0; j < 4; j++)
            bfr[j] = *(const bf16x8*)(&lsB[(wn + j * 16 + lr) * 32 + quad * 8]);
#pragma unroll
        for (int i = 0; i < 4; i++)
#pragma unroll
            for (int j = 0; j < 4; j++)
                acc[i][j] = __builtin_amdgcn_mfma_f32_16x16x32_bf16(af[i], bfr[j], acc[i][j], 0, 0, 0);
    }
    // epilogue: + bias -> bf16. D layout: row = quad*4+r, col = lane&15
#pragma unroll
    for (int j = 0; j < 4; j++) {
        const int col = tile_n + wn + j * 16 + lr;
        const float bv = bias[col];
#pragma unroll
        for (int i = 0; i < 4; i++)
#pragma unroll
            for (int r = 0; r < 4; r++) {
                const int row = tile_m + wm + i * 16 + quad * 4 + r;
                regb[(size_t)row * D_H + col] = f2b(acc[i][j][r] + bv);
            }
    }
}

// ---------------- K1 fallback: fp32 A converted in staging (R1 version) ----------------
__global__ __launch_bounds__(256)
void k_projf(const float* __restrict__ A, const unsigned short* __restrict__ Bw,
             const float* __restrict__ bias, unsigned short* __restrict__ regb) {
    __shared__ unsigned short lsA[128 * 72];
    __shared__ unsigned short lsB[128 * 72];
    const int t = threadIdx.x;
    const int tile_n = blockIdx.x * 128;
    const int tile_m = blockIdx.y * 128;
    const int w = t >> 6, l = t & 63, lr = l & 15, quad = l >> 4;
    const int wm = (w >> 1) * 64, wn = (w & 1) * 64;

    f32x4 acc[4][4];
#pragma unroll
    for (int i = 0; i < 4; i++)
#pragma unroll
        for (int j = 0; j < 4; j++) acc[i][j] = (f32x4){0.f, 0.f, 0.f, 0.f};

    const int ar = t >> 4, ac = (t & 15) * 4;
    const int br = t >> 3, bc = (t & 7) * 8;

    for (int kt = 0; kt < DBB / 64; ++kt) {
        __syncthreads();
#pragma unroll
        for (int p = 0; p < 8; p++) {
            const int row = p * 16 + ar;
            const float4 v = *(const float4*)(A + (size_t)(tile_m + row) * DBB + kt * 64 + ac);
            unsigned p0 = (unsigned)f2b(v.x) | ((unsigned)f2b(v.y) << 16);
            unsigned p1 = (unsigned)f2b(v.z) | ((unsigned)f2b(v.w) << 16);
            *(uint2*)(&lsA[row * 72 + ac]) = make_uint2(p0, p1);
        }
#pragma unroll
        for (int p = 0; p < 4; p++) {
            const int row = p * 32 + br;
            *(uint4*)(&lsB[row * 72 + bc]) =
                *(const uint4*)(Bw + (size_t)(tile_n + row) * DBB + kt * 64 + bc);
        }
        __syncthreads();
#pragma unroll
        for (int kk = 0; kk < 2; ++kk) {
            bf16x8 af[4], bfr[4];
#pragma unroll
            for (int i = 0; i < 4; i++)
                af[i] = *(const bf16x8*)(&lsA[(wm + i * 16 + lr) * 72 + kk * 32 + quad * 8]);
#pragma unroll
            for (int j = 0; j < 4; j++)
                bfr[j] = *(const bf16x8*)(&lsB[(wn + j * 16 + lr) * 72 + kk * 32 + quad * 8]);
#pragma unroll
            for (int i = 0; i < 4; i++)
#pragma unroll
                for (int j = 0; j < 4; j++)
                    acc[i][j] = __builtin_amdgcn_mfma_f32_16x16x32_bf16(af[i], bfr[j], acc[i][j], 0, 0, 0);
        }
    }
#pragma unroll
    for (int j = 0; j < 4; j++) {
        const int col = tile_n + wn + j * 16 + lr;
        const float bv = bias[col];
#pragma unroll
        for (int i = 0; i < 4; i++)
#pragma unroll
            for (int r = 0; r < 4; r++) {
                const int row = tile_m + wm + i * 16 + quad * 4 + r;
                regb[(size_t)row * D_H + col] = f2b(acc[i][j][r] + bv);
            }
    }
}

// ---------------- K2: LayerNorm (one wave per row) ----------------
__global__ __launch_bounds__(256)
void k_ln(const unsigned short* __restrict__ regb, const float* __restrict__ gamma,
          const float* __restrict__ beta, unsigned short* __restrict__ xnb) {
    const int t = threadIdx.x;
    const int wave = t >> 6, l = t & 63;
    const int r = blockIdx.x * 4 + wave;
    const int c = r & 3, b = r >> 2;

    const uint4 pk = *(const uint4*)(regb + (size_t)r * D_H + l * 8);
    const unsigned short* ps = (const unsigned short*)&pk;
    float x[8];
#pragma unroll
    for (int j = 0; j < 8; j++) x[j] = b2f(ps[j]);

    float s = 0.f, ss = 0.f;
#pragma unroll
    for (int j = 0; j < 8; j++) { s += x[j]; ss += x[j] * x[j]; }
#pragma unroll
    for (int off = 32; off > 0; off >>= 1) {
        s  += __shfl_xor(s, off);
        ss += __shfl_xor(ss, off);
    }
    const float mu  = s * (1.0f / 512.0f);
    const float var = ss * (1.0f / 512.0f) - mu * mu;
    const float rs  = rsqrtf(var + 1e-5f);

    unsigned short o[8];
#pragma unroll
    for (int j = 0; j < 8; j++) {
        const int d = l * 8 + j;
        o[j] = f2b((x[j] - mu) * rs * gamma[c * D_H + d] + beta[c * D_H + d]);
    }
    *(uint4*)(xnb + ((size_t)c * B_SZ + b) * D_H + l * 8) = *(const uint4*)o;
}

// ---------------- K3: per-camera fused gate/val GEMM + SiLU (m97 staging) ----------------
__global__ __launch_bounds__(256)
void k_swiglu(const unsigned short* __restrict__ xnb, const unsigned short* __restrict__ wg,
              const unsigned short* __restrict__ wv, unsigned short* __restrict__ hb) {
    __shared__ unsigned short lsA[128 * 32];
    __shared__ unsigned short lsG[128 * 32];
    __shared__ unsigned short lsV[128 * 32];
    const int t = threadIdx.x;
    const int tile_n = blockIdx.x * 128;
    const int tile_m = blockIdx.y * 128;
    const int cam = blockIdx.z;
    const unsigned short* Ac = xnb + (size_t)cam * B_SZ * D_H;
    const unsigned short* Gc = wg + (size_t)cam * D_H * D_H;
    const unsigned short* Vc = wv + (size_t)cam * D_H * D_H;
    const int w = t >> 6, l = t & 63, lr = l & 15, quad = l >> 4;
    const int wm = (w >> 1) * 64, wn = (w & 1) * 64;

    f32x4 ag[4][4], av[4][4];
#pragma unroll
    for (int i = 0; i < 4; i++)
#pragma unroll
        for (int j = 0; j < 4; j++) { ag[i][j] = (f32x4){0.f,0.f,0.f,0.f}; av[i][j] = (f32x4){0.f,0.f,0.f,0.f}; }

    const int srow = l >> 2, scol = (l & 3) * 8;
    const unsigned short* baseA = Ac + (size_t)(tile_m + w * 32 + srow) * D_H + scol;
    const unsigned short* baseG = Gc + (size_t)(tile_n + w * 32 + srow) * D_H + scol;
    const unsigned short* baseV = Vc + (size_t)(tile_n + w * 32 + srow) * D_H + scol;
    unsigned short* ldsAw = &lsA[w * 32 * 32];
    unsigned short* ldsGw = &lsG[w * 32 * 32];
    unsigned short* ldsVw = &lsV[w * 32 * 32];

    for (int kt = 0; kt < D_H / 32; ++kt) {
        __syncthreads();
        GLDS(baseA + kt * 32,            ldsAw);
        GLDS(baseA + kt * 32 + 16 * D_H, ldsAw + 16 * 32);
        GLDS(baseG + kt * 32,            ldsGw);
        GLDS(baseG + kt * 32 + 16 * D_H, ldsGw + 16 * 32);
        GLDS(baseV + kt * 32,            ldsVw);
        GLDS(baseV + kt * 32 + 16 * D_H, ldsVw + 16 * 32);
        __syncthreads();
        bf16x8 af[4];
#pragma unroll
        for (int i = 0; i < 4; i++)
            af[i] = *(const bf16x8*)(&lsA[(wm + i * 16 + lr) * 32 + quad * 8]);
#pragma unroll
        for (int j = 0; j < 4; j++) {
            bf16x8 gf = *(const bf16x8*)(&lsG[(wn + j * 16 + lr) * 32 + quad * 8]);
            bf16x8 vf = *(const bf16x8*)(&lsV[(wn + j * 16 + lr) * 32 + quad * 8]);
#pragma unroll
            for (int i = 0; i < 4; i++) {
                ag[i][j] = __builtin_amdgcn_mfma_f32_16x16x32_bf16(af[i], gf, ag[i][j], 0, 0, 0);
                av[i][j] = __builtin_amdgcn_mfma_f32_16x16x32_bf16(af[i], vf, av[i][j], 0, 0, 0);
            }
        }
    }
#pragma unroll
    for (int i = 0; i < 4; i++)
#pragma unroll
        for (int j = 0; j < 4; j++)
#pragma unroll
            for (int r = 0; r < 4; r++) {
                const int row = tile_m + wm + i * 16 + quad * 4 + r;
                const int col = tile_n + wn + j * 16 + lr;
                const float g = ag[i][j][r], v = av[i][j][r];
                const float h = g * v / (1.0f + __expf(-g));   // silu(g)*v
                hb[((size_t)cam * B_SZ + row) * D_H + col] = f2b(h);
            }
}

// ---------------- K4: per-camera out-proj (N padded 36->48, m97 staging) ----------------
__global__ __launch_bounds__(256)
void k_outproj(const unsigned short* __restrict__ hb, const unsigned short* __restrict__ wo,
               float* __restrict__ Abuf) {
    __shared__ unsigned short lsA[128 * 32];
    __shared__ unsigned short lsB[48 * 32];
    const int t = threadIdx.x;
    const int tile_m = blockIdx.y * 128;
    const int cam = blockIdx.z;
    const unsigned short* Ac = hb + (size_t)cam * B_SZ * D_H;
    const unsigned short* Bc = wo + (size_t)cam * 48 * D_H;
    const int w = t >> 6, l = t & 63, lr = l & 15, quad = l >> 4;
    const int srow = l >> 2, scol = (l & 3) * 8;

    f32x4 acc[2][3];
#pragma unroll
    for (int i = 0; i < 2; i++)
#pragma unroll
        for (int j = 0; j < 3; j++) acc[i][j] = (f32x4){0.f,0.f,0.f,0.f};

    const unsigned short* baseA = Ac + (size_t)(tile_m + w * 32 + srow) * D_H + scol;
    const unsigned short* baseB = Bc + (size_t)(w * 16 + srow) * D_H + scol;   // only valid w<3
    unsigned short* ldsAw = &lsA[w * 32 * 32];
    unsigned short* ldsBw = &lsB[w * 16 * 32];

    for (int kt = 0; kt < D_H / 32; ++kt) {
        __syncthreads();
        GLDS(baseA + kt * 32,            ldsAw);
        GLDS(baseA + kt * 32 + 16 * D_H, ldsAw + 16 * 32);
        if (w < 3) GLDS(baseB + kt * 32, ldsBw);
        __syncthreads();
        bf16x8 af[2], bfr[3];
#pragma unroll
        for (int i = 0; i < 2; i++)
            af[i] = *(const bf16x8*)(&lsA[(w * 32 + i * 16 + lr) * 32 + quad * 8]);
#pragma unroll
        for (int j = 0; j < 3; j++)
            bfr[j] = *(const bf16x8*)(&lsB[(j * 16 + lr) * 32 + quad * 8]);
#pragma unroll
        for (int i = 0; i < 2; i++)
#pragma unroll
            for (int j = 0; j < 3; j++)
                acc[i][j] = __builtin_amdgcn_mfma_f32_16x16x32_bf16(af[i], bfr[j], acc[i][j], 0, 0, 0);
    }
#pragma unroll
    for (int i = 0; i < 2; i++)
#pragma unroll
        for (int j = 0; j < 3; j++)
#pragma unroll
            for (int r = 0; r < 4; r++) {
                const int col = j * 16 + lr;
                if (col < 36) {
                    const int row = tile_m + w * 32 + i * 16 + quad * 4 + r;
                    Abuf[((size_t)cam * B_SZ + row) * 36 + col] = acc[i][j][r];
                }
            }
}

// ---------------- K5: skew, clip, expm (one thread per 6x6) ----------------
__global__ __launch_bounds__(128)
void k_expm(const float* __restrict__ Abuf, float* __restrict__ out) {
    const int gid = blockIdx.x * blockDim.x + threadIdx.x;
    if (gid >= B_SZ * C_CAM) return;
    const float* Ap = Abuf + (size_t)gid * 36;

    float a[36];
#pragma unroll
    for (int i = 0; i < 36; i++) a[i] = Ap[i];

    float S[36];
#pragma unroll
    for (int i = 0; i < 6; i++)
#pragma unroll
        for (int j = 0; j < 6; j++) S[i * 6 + j] = a[i * 6 + j] - a[j * 6 + i];

    float fr2 = 0.f;
#pragma unroll
    for (int i = 0; i < 36; i++) fr2 += S[i] * S[i];
    const float fr = sqrtf(fr2);
    const float sc = fminf(fr, 3.0f) / fmaxf(fr, 1e-8f) * 0.0625f;

    float As[36];
#pragma unroll
    for (int i = 0; i < 36; i++) As[i] = S[i] * sc;

    float E[36], T[36], tmp[36];
#pragma unroll
    for (int i = 0; i < 36; i++) { E[i] = (i % 7 == 0) ? 1.f : 0.f; T[i] = E[i]; }

#pragma unroll
    for (int k = 1; k <= 12; k++) {
        const float invk = 1.0f / (float)k;
#pragma unroll
        for (int i = 0; i < 6; i++)
#pragma unroll
            for (int j = 0; j < 6; j++) {
                float sum = 0.f;
#pragma unroll
                for (int q = 0; q < 6; q++) sum += T[i * 6 + q] * As[q * 6 + j];
                tmp[i * 6 + j] = sum * invk;
            }
#pragma unroll
        for (int i = 0; i < 36; i++) { T[i] = tmp[i]; E[i] += tmp[i]; }
    }
#pragma unroll
    for (int sq = 0; sq < 4; sq++) {
#pragma unroll
        for (int i = 0; i < 6; i++)
#pragma unroll
            for (int j = 0; j < 6; j++) {
                float sum = 0.f;
#pragma unroll
                for (int q = 0; q < 6; q++) sum += E[i * 6 + q] * E[q * 6 + j];
                tmp[i * 6 + j] = sum;
            }
#pragma unroll
        for (int i = 0; i < 36; i++) E[i] = tmp[i];
    }

    float* op = out + (size_t)gid * 36;
#pragma unroll
    for (int i = 0; i < 36; i++) op[i] = E[i];
}

// ---------------- launcher ----------------
extern "C" void kernel_launch(void* const* d_in, const int* in_sizes, int n_in,
                              void* d_out, int out_size, void* d_ws, size_t ws_size,
                              hipStream_t stream) {
    const float* thumb  = (const float*)d_in[0];
    const float* proj_w = (const float*)d_in[1];
    const float* proj_b = (const float*)d_in[2];
    const float* gamma  = (const float*)d_in[3];
    const float* beta   = (const float*)d_in[4];
    const float* w_gate = (const float*)d_in[5];
    const float* w_val  = (const float*)d_in[6];
    const float* w_out  = (const float*)d_in[7];

    char* ws = (char*)d_ws;
    const size_t FAST_WS = 409141248ULL;   // 268Mi A-bf16 + 64Mi regb + 64Mi xnb + weights

    if (ws_size >= FAST_WS) {
        unsigned short* Abf  = (unsigned short*)(ws);                    // 268435456 B
        unsigned short* regb = (unsigned short*)(ws + 268435456);        // 67108864 B
        unsigned short* xnb  = (unsigned short*)(ws + 335544320);        // 67108864 B
        unsigned short* hb   = (unsigned short*)(ws);                    // reuse Abf (dead after k_projb)
        float*          Abuf = (float*)(ws + 268435456);                 // reuse regb (dead after k_ln)
        unsigned short* pwb  = (unsigned short*)(ws + 402653184);        // 2 MiB
        unsigned short* wgb  = (unsigned short*)(ws + 404750336);        // 2 MiB
        unsigned short* wvb  = (unsigned short*)(ws + 406847488);        // 2 MiB
        unsigned short* wob  = (unsigned short*)(ws + 408944640);        // 192 KiB

        hipLaunchKernelGGL(k_cvt8, dim3(65536), dim3(256), 0, stream,
                           thumb, Abf, (long)B_SZ * C_CAM * DBB / 8);
        hipLaunchKernelGGL(k_cvt, dim3(1024), dim3(256), 0, stream, proj_w, pwb, D_H * DBB);
        hipLaunchKernelGGL(k_cvt, dim3(1024), dim3(256), 0, stream, w_gate, wgb, C_CAM * D_H * D_H);
        hipLaunchKernelGGL(k_cvt, dim3(1024), dim3(256), 0, stream, w_val, wvb, C_CAM * D_H * D_H);
        hipLaunchKernelGGL(k_cvt_wout, dim3((C_CAM * 48 * D_H + 255) / 256), dim3(256), 0, stream, w_out, wob);

        hipLaunchKernelGGL(k_projb, dim3(4, 512), dim3(256), 0, stream, Abf, pwb, proj_b, regb);
        hipLaunchKernelGGL(k_ln, dim3(B_SZ * C_CAM / 4), dim3(256), 0, stream, regb, gamma, beta, xnb);
        hipLaunchKernelGGL(k_swiglu, dim3(4, 128, 4), dim3(256), 0, stream, xnb, wgb, wvb, hb);
        hipLaunchKernelGGL(k_outproj, dim3(1, 128, 4), dim3(256), 0, stream, hb, wob, Abuf);
        hipLaunchKernelGGL(k_expm, dim3(B_SZ * C_CAM / 128), dim3(128), 0, stream, Abuf, (float*)d_out);
    } else {
        // fallback: fused-conversion k_proj, R1 layout (~141 MB)
        unsigned short* regb = (unsigned short*)(ws + 0);
        unsigned short* xnb  = (unsigned short*)(ws + 67108864);
        unsigned short* hb   = (unsigned short*)(ws + 0);
        float*          Abuf = (float*)(ws + 67108864);
        unsigned short* pwb  = (unsigned short*)(ws + 134217728);
        unsigned short* wgb  = (unsigned short*)(ws + 136314880);
        unsigned short* wvb  = (unsigned short*)(ws + 138412032);
        unsigned short* wob  = (unsigned short*)(ws + 140509184);

        hipLaunchKernelGGL(k_cvt, dim3(1024), dim3(256), 0, stream, proj_w, pwb, D_H * DBB);
        hipLaunchKernelGGL(k_cvt, dim3(1024), dim3(256), 0, stream, w_gate, wgb, C_CAM * D_H * D_H);
        hipLaunchKernelGGL(k_cvt, dim3(1024), dim3(256), 0, stream, w_val, wvb, C_CAM * D_H * D_H);
        hipLaunchKernelGGL(k_cvt_wout, dim3((C_CAM * 48 * D_H + 255) / 256), dim3(256), 0, stream, w_out, wob);

        hipLaunchKernelGGL(k_projf, dim3(4, 512), dim3(256), 0, stream, thumb, pwb, proj_b, regb);
        hipLaunchKernelGGL(k_ln, dim3(B_SZ * C_CAM / 4), dim3(256), 0, stream, regb, gamma, beta, xnb);
        hipLaunchKernelGGL(k_swiglu, dim3(4, 128, 4), dim3(256), 0, stream, xnb, wgb, wvb, hb);
        hipLaunchKernelGGL(k_outproj, dim3(1, 128, 4), dim3(256), 0, stream, hb, wob, Abuf);
        hipLaunchKernelGGL(k_expm, dim3(B_SZ * C_CAM / 128), dim3(128), 0, stream, Abuf, (float*)d_out);
    }
}